// Round 6
// baseline (351.041 us; speedup 1.0000x reference)
//
#include <hip/hip_runtime.h>
#include <stdint.h>

#define L_SEQ 2048
#define DMODEL 1024
#define NHEAD 16
#define HDIM 64
#define BATCH 2
#define KSPLIT 2
#define NKT (L_SEQ / 64 / KSPLIT)   // 16 k-tiles per split

typedef __attribute__((ext_vector_type(8))) short bf16x8;
typedef __attribute__((ext_vector_type(4))) float f32x4;

#define MFMA(a, b, c) __builtin_amdgcn_mfma_f32_16x16x32_bf16((a), (b), (c), 0, 0, 0)

#if __has_builtin(__builtin_amdgcn_exp2f)
#define EXP2(x) __builtin_amdgcn_exp2f(x)
#else
#define EXP2(x) exp2f(x)
#endif

#if __has_builtin(__builtin_amdgcn_wave_barrier)
#define WAVE_FENCE() __builtin_amdgcn_wave_barrier()
#else
#define WAVE_FENCE() __syncthreads()
#endif

// log2(e)/32 : folded into Q at the qkv epilogue (fixed-max softmax).
#define QSCALE 0.04508422f
// additive mask bias in exp2 domain: exp2(-100 + s) ~ 2^-99 ~ 0.
#define MASKBIAS -100.0f

__device__ __forceinline__ unsigned short f2bf(float f) {
    return (unsigned short)((__float_as_uint(f) + 0x8000u) >> 16);
}
__device__ __forceinline__ float bf2f(unsigned short h) {
    return __uint_as_float(((unsigned int)h) << 16);
}
__device__ __forceinline__ unsigned int pkbf(float a, float b) {
    return __builtin_amdgcn_perm(__float_as_uint(b) + 0x8000u,
                                 __float_as_uint(a) + 0x8000u, 0x07060302u);
}
__device__ __forceinline__ void gl2lds16(const unsigned short* g, unsigned short* l) {
    __builtin_amdgcn_global_load_lds(
        (const __attribute__((address_space(1))) void*)g,
        (__attribute__((address_space(3))) void*)l, 16, 0, 0);
}

// ---------------------------------------------------------------------------
// Merged prep kernel:
//  y<6 : fp32->bf16 convert of q,k,v / Wq,Wk,Wv
//  y==6: Wo hi/lo bf16 split
//  y==7: x<512 RoPE table; 512<=x<528 float mask-bias table (0 / -100)
// ---------------------------------------------------------------------------
__global__ void prep_kernel(
    const float* __restrict__ q, const float* __restrict__ k, const float* __restrict__ v,
    const float* __restrict__ wq, const float* __restrict__ wk, const float* __restrict__ wv,
    const float* __restrict__ Wo, const int* __restrict__ mask,
    unsigned short* __restrict__ xb, unsigned short* __restrict__ wb,
    unsigned short* __restrict__ whi, unsigned short* __restrict__ wlo,
    float2* __restrict__ ropetab, float* __restrict__ fbias)
{
    const int y = blockIdx.y, x = blockIdx.x, tid = threadIdx.x;
    if (y < 6) {
        const float* src = (y == 0) ? q : (y == 1) ? k : (y == 2) ? v
                         : (y == 3) ? wq : (y == 4) ? wk : wv;
        unsigned short* dst = (y < 3) ? xb + (size_t)y * 4194304
                                      : wb + (size_t)(y - 3) * 1048576;
        const int n = (y < 3) ? 4194304 : 1048576;
        const int i = (x * 256 + tid) * 8;
        if (i >= n) return;
        const float4 a = *(const float4*)(src + i);
        const float4 b = *(const float4*)(src + i + 4);
        uint4 u;
        u.x = pkbf(a.x, a.y); u.y = pkbf(a.z, a.w);
        u.z = pkbf(b.x, b.y); u.w = pkbf(b.z, b.w);
        *(uint4*)(dst + i) = u;
    } else if (y == 6) {
        const int i = (x * 256 + tid) * 4;
        if (i >= DMODEL * DMODEL) return;
        const float4 vv = *(const float4*)(Wo + i);
        const float f[4] = {vv.x, vv.y, vv.z, vv.w};
        union { unsigned short s[4]; uint2 u; } h, l;
#pragma unroll
        for (int r = 0; r < 4; ++r) {
            h.s[r] = f2bf(f[r]);
            l.s[r] = f2bf(f[r] - bf2f(h.s[r]));
        }
        *(uint2*)&whi[i] = h.u;
        *(uint2*)&wlo[i] = l.u;
    } else {
        if (x < 512) {
            const int idx = x * 256 + tid;
            const int l = idx >> 6, h = idx & 63;
            const float invf = powf(10000.0f, -(float)(h & 62) * (1.0f / 64.0f));
            float sn, cs;
            sincosf((float)l * invf, &sn, &cs);
            ropetab[idx] = make_float2(cs, sn);
        } else if (x < 528) {
            const int idx = (x - 512) * 256 + tid;  // 0 .. B*L-1
            fbias[idx] = (mask[idx] != 0) ? MASKBIAS : 0.0f;
        }
    }
}

// ---------------------------------------------------------------------------
// Zero kernel: clears accum (HE f32) + liacc (B*H*L f32). Must run AFTER
// qkv (accum aliases the q/k bf16 staging region of Xb) and before attn.
// ---------------------------------------------------------------------------
__global__ __launch_bounds__(256) void zero_kernel(
    float* __restrict__ accum, float* __restrict__ liacc)
{
    const size_t NA = (size_t)BATCH * NHEAD * L_SEQ * HDIM;   // 4,194,304 f32
    const size_t NL = (size_t)BATCH * NHEAD * L_SEQ;          // 65,536 f32
    const size_t i = ((size_t)blockIdx.x * 256 + threadIdx.x) * 4;
    if (i < NA) {
        *(float4*)(accum + i) = make_float4(0.f, 0.f, 0.f, 0.f);
    } else {
        const size_t j = i - NA;
        if (j < NL) *(float4*)(liacc + j) = make_float4(0.f, 0.f, 0.f, 0.f);
    }
}

// ---------------------------------------------------------------------------
// Kernel A: QKV projection (unchanged; Q scaled by QSCALE).
// ---------------------------------------------------------------------------
__global__ __launch_bounds__(256) void qkv_kernel(
    const unsigned short* __restrict__ Xb, const unsigned short* __restrict__ Wb,
    const float* __restrict__ bq, const float* __restrict__ bk, const float* __restrict__ bv,
    const float2* __restrict__ ropetab,
    unsigned short* __restrict__ Qd, unsigned short* __restrict__ Kd,
    unsigned short* __restrict__ Vd)
{
    const int id = blockIdx.x;
    const int bx = id / 96, rem = id % 96;
    const int z = rem >> 5, by = rem & 31;

    const unsigned short* X = Xb + (size_t)z * (BATCH * L_SEQ * DMODEL);
    const unsigned short* W = Wb + (size_t)z * (DMODEL * DMODEL);
    const float* bias = (z == 0) ? bq : (z == 1) ? bk : bv;

    __shared__ __align__(16) unsigned short As[128 * 64];
    __shared__ __align__(16) unsigned short Bs[128 * 64];

    const int tid  = threadIdx.x;
    const int wave = tid >> 6, lane = tid & 63;
    const int ml = lane & 15, kq = lane >> 4;
    const int m0 = by * 128, n0 = bx * 128;
    const int wm = (wave & 1) * 64, wn = (wave >> 1) * 64;

    f32x4 acc[4][4];
#pragma unroll
    for (int i = 0; i < 4; ++i)
#pragma unroll
        for (int j = 0; j < 4; ++j) acc[i][j] = (f32x4){0.f, 0.f, 0.f, 0.f};

    const int prow = wave * 32 + (lane >> 3);
    const int pch  = (lane & 7) ^ ((lane >> 3) & 7);
    const unsigned short* gA = X + (size_t)(m0 + prow) * DMODEL + pch * 8;
    const unsigned short* gB = W + (size_t)(n0 + prow) * DMODEL + pch * 8;
    unsigned short* lA = As + wave * 2048;
    unsigned short* lB = Bs + wave * 2048;

    for (int kc = 0; kc < DMODEL; kc += 64) {
#pragma unroll
        for (int qq = 0; qq < 4; ++qq) {
            gl2lds16(gA + kc + (size_t)qq * 8 * DMODEL, lA + qq * 512);
            gl2lds16(gB + kc + (size_t)qq * 8 * DMODEL, lB + qq * 512);
        }
        __syncthreads();

        bf16x8 af[2][4], bfv[2][4];
#pragma unroll
        for (int ks = 0; ks < 2; ++ks)
#pragma unroll
            for (int i = 0; i < 4; ++i) {
                const int Ra = wm + i * 16 + ml;
                af[ks][i] = *(const bf16x8*)&As[Ra * 64 + (((ks * 4 + kq) ^ (Ra & 7)) << 3)];
                const int Rb = wn + i * 16 + ml;
                bfv[ks][i] = *(const bf16x8*)&Bs[Rb * 64 + (((ks * 4 + kq) ^ (Rb & 7)) << 3)];
            }
#pragma unroll
        for (int ks = 0; ks < 2; ++ks)
#pragma unroll
            for (int i = 0; i < 4; ++i)
#pragma unroll
                for (int j = 0; j < 4; ++j)
                    acc[i][j] = MFMA(af[ks][i], bfv[ks][j], acc[i][j]);
        __syncthreads();
    }

    if (z < 2) {
        unsigned short* dst = (z == 0) ? Qd : Kd;
        const float osc = (z == 0) ? QSCALE : 1.0f;
#pragma unroll
        for (int jt = 0; jt < 4; ++jt) {
            const int col = n0 + wn + jt * 16 + ml;
            const float bv = bias[col];
            const int nh = col >> 6, hh = col & 63;
            const int odd = hh & 1;
#pragma unroll
            for (int it = 0; it < 4; ++it) {
#pragma unroll
                for (int r = 0; r < 4; ++r) {
                    const int row = m0 + wm + it * 16 + kq * 4 + r;
                    const int bb = row >> 11, ll = row & 2047;
                    const float v = acc[it][jt][r] + bv;
                    const float partner = __shfl_xor(v, 1);
                    const float2 cs = ropetab[ll * 64 + hh];
                    const float res = odd ? fmaf(v, cs.x, partner * cs.y)
                                          : fmaf(v, cs.x, -partner * cs.y);
                    dst[(((size_t)(bb * NHEAD + nh) * L_SEQ + ll) << 6) + hh] = f2bf(res * osc);
                }
            }
        }
    } else {
#pragma unroll
        for (int jt = 0; jt < 4; ++jt) {
            const int col = n0 + wn + jt * 16 + ml;
            const float bv = bias[col];
            const int nh = col >> 6, hh = col & 63;
#pragma unroll
            for (int it = 0; it < 4; ++it) {
                const int rb = m0 + wm + it * 16 + kq * 4;
                const int bb = rb >> 11, ll = rb & 2047;
                uint2 pk;
                pk.x = pkbf(acc[it][jt][0] + bv, acc[it][jt][1] + bv);
                pk.y = pkbf(acc[it][jt][2] + bv, acc[it][jt][3] + bv);
                *(uint2*)&Vd[(((size_t)bb * NHEAD + nh) * HDIM + hh) * L_SEQ + ll] = pk;
            }
        }
    }
}

// ---------------------------------------------------------------------------
// Kernel B: flash attention, R3-verified core + 2-way K-split.
// R3 (248.9us) was occupancy-capped: 512 blocks = 2 blocks/CU (grid-
// structural), VALUBusy 44 / MfmaUtil 22 / LDS ~40% — no pipe saturated.
// Split: 1024 blocks (sp = id>>9 so both splits of a (bh,qb) share an XCD);
// each split covers 1024 keys (16 tiles). Partials combine via f32 atomicAdd
// into zeroed accum/liacc (commutative -> deterministic); norm_kernel then
// normalizes + hi/lo-splits into AOhi/AOlo. LDS 48 KB -> 3 blocks/CU now
// reachable (grid 4/CU). li: scalar adds + shfl (R5: ones-MFMA li was
// correct but SLOWER — latency-bound chain). pkbf packing (R4: cvtpk
// miscompiles/hazards — dropped).
// ---------------------------------------------------------------------------
__global__ __launch_bounds__(256) void attn_kernel(
    const unsigned short* __restrict__ Qr, const unsigned short* __restrict__ Kr,
    const unsigned short* __restrict__ Vt, const float* __restrict__ fbias,
    float* __restrict__ accum, float* __restrict__ liacc)
{
    __shared__ __align__(16) unsigned short Ks[2][64 * 64];  // 16 KB
    __shared__ __align__(16) unsigned short Vs[2][64 * 64];  // 16 KB
    __shared__ __align__(16) unsigned short Ps[4][32 * 64];  // 16 KB (per-wave)

    const int tid  = threadIdx.x;
    const int wave = tid >> 6, lane = tid & 63;
    const int ml = lane & 15, kq = lane >> 4;

    // 1024 blocks: split-major-top, then xcd-major as before.
    const int id = blockIdx.x;
    const int sp  = id >> 9;                      // 0..1 K-split
    const int rid = id & 511;
    const int xcd = rid & 7, slot = rid >> 3;     // slot 0..63
    const int bh = xcd * 4 + (slot & 3);
    const int qb = slot >> 2;                     // 0..15
    const int b = bh >> 4;
    const int q0 = qb * 128;
    const int wq = wave * 32;
    const int koff = sp * (L_SEQ / KSPLIT);       // 0 or 1024

    const unsigned short* Qp = Qr + (size_t)bh * L_SEQ * HDIM;
    const unsigned short* Kp = Kr + (size_t)bh * L_SEQ * HDIM;
    const unsigned short* Vp = Vt + (size_t)bh * HDIM * L_SEQ;

    // Q fragments: 32 q rows per wave (q = qt*16 + ml).
    bf16x8 qf[2][2];
#pragma unroll
    for (int qt = 0; qt < 2; ++qt)
#pragma unroll
        for (int c = 0; c < 2; ++c)
            qf[qt][c] = *(const bf16x8*)(Qp + (size_t)(q0 + wq + qt * 16 + ml) * HDIM + c * 32 + kq * 8);

    float li[2] = {0.f, 0.f};
    f32x4 o[2][4];
#pragma unroll
    for (int qt = 0; qt < 2; ++qt)
#pragma unroll
        for (int ht = 0; ht < 4; ++ht) o[qt][ht] = (f32x4){0.f, 0.f, 0.f, 0.f};

    unsigned short* Pw = Ps[wave];

    // Staging: wave stages rows [wave*16, +16) of K and V, 2 issues of 8 rows.
    const int srow8 = lane >> 3;
    const int sch   = (lane & 7) ^ srow8;
    const unsigned short* gK = Kp + (size_t)(koff + wave * 16 + srow8) * HDIM + sch * 8;
    const unsigned short* gV = Vp + (size_t)(wave * 16 + srow8) * L_SEQ + koff + sch * 8;

#define STAGE(kt, bf)                                                          \
    do {                                                                       \
        gl2lds16(gK + (size_t)((kt) * 64) * HDIM, &Ks[bf][(wave * 16) * 64]);  \
        gl2lds16(gK + (size_t)((kt) * 64 + 8) * HDIM,                          \
                 &Ks[bf][(wave * 16 + 8) * 64]);                               \
        gl2lds16(gV + (kt) * 64, &Vs[bf][(wave * 16) * 64]);                   \
        gl2lds16(gV + (size_t)8 * L_SEQ + (kt) * 64,                           \
                 &Vs[bf][(wave * 16 + 8) * 64]);                               \
    } while (0)

    // Mask-bias quads: key = koff + kt*64 + nt*16 + kq*4 + r, matching the
    // QK MFMA C/D row layout. Reg double-buffered one tile ahead.
    const float* fbp = fbias + (size_t)b * L_SEQ + koff + kq * 4;
    f32x4 bcur[4], bnext[4];
#pragma unroll
    for (int nt = 0; nt < 4; ++nt) bcur[nt] = *(const f32x4*)(fbp + nt * 16);

    STAGE(0, 0);

    for (int kt = 0; kt < NKT; ++kt) {
        const int buf = kt & 1;
        __syncthreads();                       // tile kt staged
        if (kt + 1 < NKT) {
            STAGE(kt + 1, buf ^ 1);
#pragma unroll
            for (int nt = 0; nt < 4; ++nt)
                bnext[nt] = *(const f32x4*)(fbp + (kt + 1) * 64 + nt * 16);
        }

        const unsigned short* Kb = Ks[buf];
        const unsigned short* Vb = Vs[buf];

        // S^T = K·Q^T + maskbias : K-frags read once, used for both q-subtiles.
        f32x4 st[2][4];
#pragma unroll
        for (int nt = 0; nt < 4; ++nt) {
            const int R = nt * 16 + ml;
            const bf16x8 kf0 = *(const bf16x8*)&Kb[R * 64 + ((kq ^ (R & 7)) << 3)];
            const bf16x8 kf1 = *(const bf16x8*)&Kb[R * 64 + (((4 + kq) ^ (R & 7)) << 3)];
#pragma unroll
            for (int qt = 0; qt < 2; ++qt) {
                f32x4 c = MFMA(kf0, qf[qt][0], bcur[nt]);
                c = MFMA(kf1, qf[qt][1], c);
                st[qt][nt] = c;
            }
        }

        // Fixed-max softmax; P -> per-wave LDS (swizzled, unpadded).
        // Masked entries: exp2(-100 + s) ~ 0 (no per-element select needed).
#pragma unroll
        for (int qt = 0; qt < 2; ++qt) {
#pragma unroll
            for (int nt = 0; nt < 4; ++nt) {
                float p[4];
#pragma unroll
                for (int r = 0; r < 4; ++r) {
                    p[r] = EXP2(st[qt][nt][r]);
                    li[qt] += p[r];
                }
                uint2 pk;
                pk.x = pkbf(p[0], p[1]);
                pk.y = pkbf(p[2], p[3]);
                const int row = qt * 16 + ml;
                const int ck = nt * 2 + (kq >> 1);
                *(uint2*)&Pw[row * 64 + ((ck ^ (ml & 7)) << 3) + (kq & 1) * 4] = pk;
            }
        }
        WAVE_FENCE();

        // O^T += V^T·P : V-frags read once, used for both q-subtiles.
        bf16x8 pf[2][2];
#pragma unroll
        for (int qt = 0; qt < 2; ++qt) {
            const int row = qt * 16 + ml;
            pf[qt][0] = *(const bf16x8*)&Pw[row * 64 + ((kq ^ (ml & 7)) << 3)];
            pf[qt][1] = *(const bf16x8*)&Pw[row * 64 + (((4 + kq) ^ (ml & 7)) << 3)];
        }
#pragma unroll
        for (int ht = 0; ht < 4; ++ht) {
            const int R = ht * 16 + ml;
            const bf16x8 vf0 = *(const bf16x8*)&Vb[R * 64 + ((kq ^ (R & 7)) << 3)];
            const bf16x8 vf1 = *(const bf16x8*)&Vb[R * 64 + (((4 + kq) ^ (R & 7)) << 3)];
#pragma unroll
            for (int qt = 0; qt < 2; ++qt) {
                o[qt][ht] = MFMA(vf0, pf[qt][0], o[qt][ht]);
                o[qt][ht] = MFMA(vf1, pf[qt][1], o[qt][ht]);
            }
        }
        WAVE_FENCE();  // Pw reads done before next tile overwrites

        // rotate bias double-buffer (static indices; dead copy on last iter)
#pragma unroll
        for (int nt = 0; nt < 4; ++nt) bcur[nt] = bnext[nt];
    }
#undef STAGE

    // li spans lanes ml, ml+16, ml+32, ml+48 -> full split-partial sum.
#pragma unroll
    for (int qt = 0; qt < 2; ++qt) {
        li[qt] += __shfl_xor(li[qt], 16);
        li[qt] += __shfl_xor(li[qt], 32);
    }

    // Epilogue: unnormalized partial accumulate. accum layout [bh][q][h] f32.
    // O^T lane holds (h = ht*16 + kq*4 + r, q = qt*16 + ml). 32 atomics/lane,
    // fire-and-forget; f32 add commutes -> bit-deterministic across splits.
    float* accb = accum + ((size_t)bh * L_SEQ + q0 + wq) * HDIM;
#pragma unroll
    for (int qt = 0; qt < 2; ++qt) {
#pragma unroll
        for (int ht = 0; ht < 4; ++ht) {
            const int base = (qt * 16 + ml) * HDIM + ht * 16 + kq * 4;
#pragma unroll
            for (int r = 0; r < 4; ++r)
                atomicAdd(accb + base + r, o[qt][ht][r]);
        }
    }
    if (kq == 0) {
#pragma unroll
        for (int qt = 0; qt < 2; ++qt)
            atomicAdd(liacc + (size_t)bh * L_SEQ + q0 + wq + qt * 16 + ml, li[qt]);
    }
}

// ---------------------------------------------------------------------------
// Normalize kernel: AO = accum / liacc, hi/lo bf16 split, head-interleaved
// row-major AO layout (row = b*L + q, col = nh*64 + h). 512 blocks.
// ---------------------------------------------------------------------------
__global__ __launch_bounds__(256) void norm_kernel(
    const float* __restrict__ accum, const float* __restrict__ liacc,
    unsigned short* __restrict__ AOhi, unsigned short* __restrict__ AOlo)
{
    const int id = blockIdx.x;            // bh*16 + qb
    const int bh = id >> 4, qb = id & 15;
    const int b = bh >> 4, nh = bh & 15;
    const int t = threadIdx.x;
    const int h = t & 63, qq = t >> 6;    // 4 q-rows per pass
    const float* ap = accum + ((size_t)bh * L_SEQ + qb * 128) * HDIM;
    const float* lp = liacc + (size_t)bh * L_SEQ + qb * 128;
#pragma unroll 4
    for (int p = 0; p < 32; ++p) {
        const int ql = p * 4 + qq;
        const float inv = 1.0f / lp[ql];
        const float v = ap[ql * 64 + h] * inv;
        const unsigned short hi = f2bf(v);
        const unsigned short lo = f2bf(v - bf2f(hi));
        const size_t g = ((size_t)b * L_SEQ + qb * 128 + ql) * DMODEL + nh * 64 + h;
        AOhi[g] = hi;
        AOlo[g] = lo;
    }
}

// ---------------------------------------------------------------------------
// Kernel C: out = AO @ Wo^T + bo, 3-term bf16-split. 128x64 tiles, 512
// blocks = 2 blocks/CU. id%8 == by%8 -> A-panel XCD colocation.
// ---------------------------------------------------------------------------
__global__ __launch_bounds__(256) void oproj_kernel(
    const unsigned short* __restrict__ Ahi_g, const unsigned short* __restrict__ Alo_g,
    const unsigned short* __restrict__ Whi_g, const unsigned short* __restrict__ Wlo_g,
    const float* __restrict__ bias, float* __restrict__ out)
{
    const int id = blockIdx.x;
    const int bxn = id >> 5, by = id & 31;

    __shared__ __align__(16) unsigned short Ah[128 * 32], Al[128 * 32];  // 8 KB ea
    __shared__ __align__(16) unsigned short Bh[64 * 32],  Bl[64 * 32];   // 4 KB ea

    const int tid  = threadIdx.x;
    const int wave = tid >> 6, lane = tid & 63;
    const int ml = lane & 15, kq = lane >> 4;
    const int m0 = by * 128, n0 = bxn * 64;
    const int wm = (wave & 1) * 64, wn = (wave >> 1) * 32;

    f32x4 acc[4][2];
#pragma unroll
    for (int i = 0; i < 4; ++i)
#pragma unroll
        for (int j = 0; j < 2; ++j) acc[i][j] = (f32x4){0.f, 0.f, 0.f, 0.f};

    const int rl  = lane >> 2;                       // 0..15 rows per issue
    const int pch = (lane & 3) ^ ((lane >> 3) & 3);
    const int prowA = wave * 32 + rl;
    const int prowB = wave * 16 + rl;
    const unsigned short* gAh = Ahi_g + (size_t)(m0 + prowA) * DMODEL + pch * 8;
    const unsigned short* gAl = Alo_g + (size_t)(m0 + prowA) * DMODEL + pch * 8;
    const unsigned short* gBh = Whi_g + (size_t)(n0 + prowB) * DMODEL + pch * 8;
    const unsigned short* gBl = Wlo_g + (size_t)(n0 + prowB) * DMODEL + pch * 8;
    unsigned short* lAh = Ah + wave * 1024;
    unsigned short* lAl = Al + wave * 1024;
    unsigned short* lBh = Bh + wave * 512;
    unsigned short* lBl = Bl + wave * 512;

    for (int kc = 0; kc < DMODEL; kc += 32) {
#pragma unroll
        for (int qq = 0; qq < 2; ++qq) {
            const size_t go = kc + (size_t)qq * 16 * DMODEL;
            gl2lds16(gAh + go, lAh + qq * 512);
            gl2lds16(gAl + go, lAl + qq * 512);
        }
        gl2lds16(gBh + kc, lBh);
        gl2lds16(gBl + kc, lBl);
        __syncthreads();

        bf16x8 ah[4], al[4], bh_[2], bl_[2];
#pragma unroll
        for (int i = 0; i < 4; ++i) {
            const int Ra = wm + i * 16 + ml;
            const int sa = Ra * 32 + ((kq ^ ((Ra >> 1) & 3)) << 3);
            ah[i] = *(const bf16x8*)&Ah[sa];
            al[i] = *(const bf16x8*)&Al[sa];
        }
#pragma unroll
        for (int j = 0; j < 2; ++j) {
            const int Rb = wn + j * 16 + ml;
            const int sb = Rb * 32 + ((kq ^ ((Rb >> 1) & 3)) << 3);
            bh_[j] = *(const bf16x8*)&Bh[sb];
            bl_[j] = *(const bf16x8*)&Bl[sb];
        }
#pragma unroll
        for (int i = 0; i < 4; ++i)
#pragma unroll
            for (int j = 0; j < 2; ++j) {
                acc[i][j] = MFMA(ah[i], bh_[j], acc[i][j]);
                acc[i][j] = MFMA(al[i], bh_[j], acc[i][j]);
                acc[i][j] = MFMA(ah[i], bl_[j], acc[i][j]);
            }
        __syncthreads();
    }

#pragma unroll
    for (int jt = 0; jt < 2; ++jt) {
        const int col = n0 + wn + jt * 16 + ml;
        const float bv = bias[col];
#pragma unroll
        for (int it = 0; it < 4; ++it)
#pragma unroll
            for (int r = 0; r < 4; ++r) {
                const int row = m0 + wm + it * 16 + kq * 4 + r;
                out[(size_t)row * DMODEL + col] = acc[it][jt][r] + bv;
            }
    }
}

extern "C" void kernel_launch(void* const* d_in, const int* in_sizes, int n_in,
                              void* d_out, int out_size, void* d_ws, size_t ws_size,
                              hipStream_t stream)
{
    (void)in_sizes; (void)n_in; (void)out_size; (void)ws_size;
    const float* q    = (const float*)d_in[0];
    const float* k    = (const float*)d_in[1];
    const float* v    = (const float*)d_in[2];
    const int*   mask = (const int*)d_in[3];
    const float* Wq   = (const float*)d_in[4];
    const float* bq   = (const float*)d_in[5];
    const float* Wk   = (const float*)d_in[6];
    const float* bk   = (const float*)d_in[7];
    const float* Wv   = (const float*)d_in[8];
    const float* bv   = (const float*)d_in[9];
    const float* Wo   = (const float*)d_in[10];
    const float* bo   = (const float*)d_in[11];
    float* out = (float*)d_out;

    const size_t HE = (size_t)BATCH * NHEAD * L_SEQ * HDIM;   // 4,194,304
    const size_t DD = (size_t)DMODEL * DMODEL;                // 1,048,576
    unsigned short* Xb   = (unsigned short*)d_ws;             // 3*HE shorts
    unsigned short* Wb   = Xb + 3 * HE;                       // 3*DD shorts
    unsigned short* Qr   = Wb + 3 * DD;
    unsigned short* Kr   = Qr + HE;
    unsigned short* Vt   = Kr + HE;
    unsigned short* Whi  = Vt + HE;
    unsigned short* Wlo  = Whi + DD;
    float* fbias = (float*)(Wlo + DD);                        // 16 KB
    float2* ropetab = (float2*)(fbias + (size_t)BATCH * L_SEQ);
    float* liacc = (float*)(ropetab + (size_t)L_SEQ * 64);    // 256 KB

    // Aliases (stream-ordered safety):
    //  accum (HE f32 = 2*HE shorts) over Xb[0..2HE): q/k bf16 dead after qkv;
    //    zero_kernel runs after qkv, attn atomics after that.
    //  AOhi = Xb + 2HE (v bf16 slice, dead after qkv; written by norm).
    //  AOlo = Qr (dead after attn; norm runs after attn, oproj reads after).
    float* accum = (float*)Xb;
    unsigned short* AOhi = Xb + 2 * HE;
    unsigned short* AOlo = Qr;

    prep_kernel<<<dim3(2048, 8), dim3(256), 0, stream>>>(
        q, k, v, Wq, Wk, Wv, Wo, mask, Xb, Wb, Whi, Wlo, ropetab, fbias);

    qkv_kernel<<<dim3(768), dim3(256), 0, stream>>>(Xb, Wb, bq, bk, bv, ropetab, Qr, Kr, Vt);

    zero_kernel<<<dim3(4160), dim3(256), 0, stream>>>(accum, liacc);

    attn_kernel<<<dim3(1024), dim3(256), 0, stream>>>(Qr, Kr, Vt, fbias, accum, liacc);

    norm_kernel<<<dim3(512), dim3(256), 0, stream>>>(accum, liacc, AOhi, AOlo);

    oproj_kernel<<<dim3(512), dim3(256), 0, stream>>>(AOhi, AOlo, Whi, Wlo, bo, out);
}

// Round 7
// 246.537 us; speedup vs baseline: 1.4239x; 1.4239x over previous
//
#include <hip/hip_runtime.h>
#include <stdint.h>

#define L_SEQ 2048
#define DMODEL 1024
#define NHEAD 16
#define HDIM 64
#define BATCH 2
#define KVBLK 32
#define KHALF (L_SEQ / 2)
#define NKT (KHALF / KVBLK)   // 32 k-tiles per kh-half

typedef __attribute__((ext_vector_type(8))) short bf16x8;
typedef __attribute__((ext_vector_type(4))) float f32x4;

#define MFMA(a, b, c) __builtin_amdgcn_mfma_f32_16x16x32_bf16((a), (b), (c), 0, 0, 0)

#if __has_builtin(__builtin_amdgcn_exp2f)
#define EXP2(x) __builtin_amdgcn_exp2f(x)
#else
#define EXP2(x) exp2f(x)
#endif

#if __has_builtin(__builtin_amdgcn_wave_barrier)
#define WAVE_FENCE() __builtin_amdgcn_wave_barrier()
#else
#define WAVE_FENCE() __syncthreads()
#endif

// log2(e)/32 : folded into Q at the qkv epilogue (fixed-max softmax).
#define QSCALE 0.04508422f
// additive mask bias in exp2 domain: exp2(-100 + s) ~ 2^-99 ~ 0.
#define MASKBIAS -100.0f

__device__ __forceinline__ unsigned short f2bf(float f) {
    return (unsigned short)((__float_as_uint(f) + 0x8000u) >> 16);
}
__device__ __forceinline__ float bf2f(unsigned short h) {
    return __uint_as_float(((unsigned int)h) << 16);
}
__device__ __forceinline__ unsigned int pkbf(float a, float b) {
    return __builtin_amdgcn_perm(__float_as_uint(b) + 0x8000u,
                                 __float_as_uint(a) + 0x8000u, 0x07060302u);
}
__device__ __forceinline__ void gl2lds16(const unsigned short* g, unsigned short* l) {
    __builtin_amdgcn_global_load_lds(
        (const __attribute__((address_space(1))) void*)g,
        (__attribute__((address_space(3))) void*)l, 16, 0, 0);
}

// ---------------------------------------------------------------------------
// Merged prep kernel:
//  y<6 : fp32->bf16 convert of q,k,v / Wq,Wk,Wv
//  y==6: Wo hi/lo bf16 split
//  y==7: x<512 RoPE table; 512<=x<528 float mask-bias table (0 / -100)
// ---------------------------------------------------------------------------
__global__ void prep_kernel(
    const float* __restrict__ q, const float* __restrict__ k, const float* __restrict__ v,
    const float* __restrict__ wq, const float* __restrict__ wk, const float* __restrict__ wv,
    const float* __restrict__ Wo, const int* __restrict__ mask,
    unsigned short* __restrict__ xb, unsigned short* __restrict__ wb,
    unsigned short* __restrict__ whi, unsigned short* __restrict__ wlo,
    float2* __restrict__ ropetab, float* __restrict__ fbias)
{
    const int y = blockIdx.y, x = blockIdx.x, tid = threadIdx.x;
    if (y < 6) {
        const float* src = (y == 0) ? q : (y == 1) ? k : (y == 2) ? v
                         : (y == 3) ? wq : (y == 4) ? wk : wv;
        unsigned short* dst = (y < 3) ? xb + (size_t)y * 4194304
                                      : wb + (size_t)(y - 3) * 1048576;
        const int n = (y < 3) ? 4194304 : 1048576;
        const int i = (x * 256 + tid) * 8;
        if (i >= n) return;
        const float4 a = *(const float4*)(src + i);
        const float4 b = *(const float4*)(src + i + 4);
        uint4 u;
        u.x = pkbf(a.x, a.y); u.y = pkbf(a.z, a.w);
        u.z = pkbf(b.x, b.y); u.w = pkbf(b.z, b.w);
        *(uint4*)(dst + i) = u;
    } else if (y == 6) {
        const int i = (x * 256 + tid) * 4;
        if (i >= DMODEL * DMODEL) return;
        const float4 vv = *(const float4*)(Wo + i);
        const float f[4] = {vv.x, vv.y, vv.z, vv.w};
        union { unsigned short s[4]; uint2 u; } h, l;
#pragma unroll
        for (int r = 0; r < 4; ++r) {
            h.s[r] = f2bf(f[r]);
            l.s[r] = f2bf(f[r] - bf2f(h.s[r]));
        }
        *(uint2*)&whi[i] = h.u;
        *(uint2*)&wlo[i] = l.u;
    } else {
        if (x < 512) {
            const int idx = x * 256 + tid;
            const int l = idx >> 6, h = idx & 63;
            const float invf = powf(10000.0f, -(float)(h & 62) * (1.0f / 64.0f));
            float sn, cs;
            sincosf((float)l * invf, &sn, &cs);
            ropetab[idx] = make_float2(cs, sn);
        } else if (x < 528) {
            const int idx = (x - 512) * 256 + tid;  // 0 .. B*L-1
            fbias[idx] = (mask[idx] != 0) ? MASKBIAS : 0.0f;
        }
    }
}

// ---------------------------------------------------------------------------
// Kernel A: QKV projection (unchanged; Q scaled by QSCALE).
// ---------------------------------------------------------------------------
__global__ __launch_bounds__(256) void qkv_kernel(
    const unsigned short* __restrict__ Xb, const unsigned short* __restrict__ Wb,
    const float* __restrict__ bq, const float* __restrict__ bk, const float* __restrict__ bv,
    const float2* __restrict__ ropetab,
    unsigned short* __restrict__ Qd, unsigned short* __restrict__ Kd,
    unsigned short* __restrict__ Vd)
{
    const int id = blockIdx.x;
    const int bx = id / 96, rem = id % 96;
    const int z = rem >> 5, by = rem & 31;

    const unsigned short* X = Xb + (size_t)z * (BATCH * L_SEQ * DMODEL);
    const unsigned short* W = Wb + (size_t)z * (DMODEL * DMODEL);
    const float* bias = (z == 0) ? bq : (z == 1) ? bk : bv;

    __shared__ __align__(16) unsigned short As[128 * 64];
    __shared__ __align__(16) unsigned short Bs[128 * 64];

    const int tid  = threadIdx.x;
    const int wave = tid >> 6, lane = tid & 63;
    const int ml = lane & 15, kq = lane >> 4;
    const int m0 = by * 128, n0 = bx * 128;
    const int wm = (wave & 1) * 64, wn = (wave >> 1) * 64;

    f32x4 acc[4][4];
#pragma unroll
    for (int i = 0; i < 4; ++i)
#pragma unroll
        for (int j = 0; j < 4; ++j) acc[i][j] = (f32x4){0.f, 0.f, 0.f, 0.f};

    const int prow = wave * 32 + (lane >> 3);
    const int pch  = (lane & 7) ^ ((lane >> 3) & 7);
    const unsigned short* gA = X + (size_t)(m0 + prow) * DMODEL + pch * 8;
    const unsigned short* gB = W + (size_t)(n0 + prow) * DMODEL + pch * 8;
    unsigned short* lA = As + wave * 2048;
    unsigned short* lB = Bs + wave * 2048;

    for (int kc = 0; kc < DMODEL; kc += 64) {
#pragma unroll
        for (int qq = 0; qq < 4; ++qq) {
            gl2lds16(gA + kc + (size_t)qq * 8 * DMODEL, lA + qq * 512);
            gl2lds16(gB + kc + (size_t)qq * 8 * DMODEL, lB + qq * 512);
        }
        __syncthreads();

        bf16x8 af[2][4], bfv[2][4];
#pragma unroll
        for (int ks = 0; ks < 2; ++ks)
#pragma unroll
            for (int i = 0; i < 4; ++i) {
                const int Ra = wm + i * 16 + ml;
                af[ks][i] = *(const bf16x8*)&As[Ra * 64 + (((ks * 4 + kq) ^ (Ra & 7)) << 3)];
                const int Rb = wn + i * 16 + ml;
                bfv[ks][i] = *(const bf16x8*)&Bs[Rb * 64 + (((ks * 4 + kq) ^ (Rb & 7)) << 3)];
            }
#pragma unroll
        for (int ks = 0; ks < 2; ++ks)
#pragma unroll
            for (int i = 0; i < 4; ++i)
#pragma unroll
                for (int j = 0; j < 4; ++j)
                    acc[i][j] = MFMA(af[ks][i], bfv[ks][j], acc[i][j]);
        __syncthreads();
    }

    if (z < 2) {
        unsigned short* dst = (z == 0) ? Qd : Kd;
        const float osc = (z == 0) ? QSCALE : 1.0f;
#pragma unroll
        for (int jt = 0; jt < 4; ++jt) {
            const int col = n0 + wn + jt * 16 + ml;
            const float bv = bias[col];
            const int nh = col >> 6, hh = col & 63;
            const int odd = hh & 1;
#pragma unroll
            for (int it = 0; it < 4; ++it) {
#pragma unroll
                for (int r = 0; r < 4; ++r) {
                    const int row = m0 + wm + it * 16 + kq * 4 + r;
                    const int bb = row >> 11, ll = row & 2047;
                    const float v = acc[it][jt][r] + bv;
                    const float partner = __shfl_xor(v, 1);
                    const float2 cs = ropetab[ll * 64 + hh];
                    const float res = odd ? fmaf(v, cs.x, partner * cs.y)
                                          : fmaf(v, cs.x, -partner * cs.y);
                    dst[(((size_t)(bb * NHEAD + nh) * L_SEQ + ll) << 6) + hh] = f2bf(res * osc);
                }
            }
        }
    } else {
#pragma unroll
        for (int jt = 0; jt < 4; ++jt) {
            const int col = n0 + wn + jt * 16 + ml;
            const float bv = bias[col];
            const int nh = col >> 6, hh = col & 63;
#pragma unroll
            for (int it = 0; it < 4; ++it) {
                const int rb = m0 + wm + it * 16 + kq * 4;
                const int bb = rb >> 11, ll = rb & 2047;
                uint2 pk;
                pk.x = pkbf(acc[it][jt][0] + bv, acc[it][jt][1] + bv);
                pk.y = pkbf(acc[it][jt][2] + bv, acc[it][jt][3] + bv);
                *(uint2*)&Vd[(((size_t)bb * NHEAD + nh) * HDIM + hh) * L_SEQ + ll] = pk;
            }
        }
    }
}

// ---------------------------------------------------------------------------
// Kernel B: flash attention, 8 waves (512 thr): wave = (kh, qg).
// R6 post-mortem: cross-block K-split via atomics = 131 MB RMW writes, 155us
// (dropped). R3 (61us) is stall-bound at 2 waves/SIMD (issue-cycle model
// ~6us << 61us; no pipe >45%). This round: K-split WITHIN the block ->
// 16 waves/CU (4/SIMD) with NO atomics. Wave (kh,qg) = q rows qg*32..+32,
// keys kh*1024..+1024 in 32-key tiles. Per-kh dbuf K/V LDS; per-wave P.
// End: kh=1 dumps o(f32)+li to LDS (dead K/V region), kh=0 adds and runs
// the unchanged R3 epilogue. Grid 512, LDS 48.5 KB, all-R3 arithmetic.
// ---------------------------------------------------------------------------
__global__ __launch_bounds__(512, 4) void attn_kernel(
    const unsigned short* __restrict__ Qr, const unsigned short* __restrict__ Kr,
    const unsigned short* __restrict__ Vt, const float* __restrict__ fbias,
    unsigned short* __restrict__ AOhi, unsigned short* __restrict__ AOlo)
{
    // Manual carve, 49664 B:
    //  [0,8192)      Ks[dbuf][kh] : 32 x 64 shorts (4 KB each)
    //  [8192,16384)  Vs[dbuf][kh] : 64 x 32 shorts (4 KB each)
    //  [16384,24576) Ps[w]        : 32 x 32 shorts (2 KB each, per wave)
    //  [24576,24832) lis          : float[128]
    __shared__ __align__(16) unsigned short lds[24832];

    const int tid  = threadIdx.x;
    const int w    = tid >> 6, lane = tid & 63;
    const int kh   = w >> 2, qg = w & 3;
    const int ml = lane & 15, kq = lane >> 4;

    // 512 blocks: xcd-major, 4 bh per XCD (same as R3).
    const int id = blockIdx.x;
    const int xcd = id & 7, slot = id >> 3;       // slot 0..63
    const int bh = xcd * 4 + (slot & 3);
    const int qb = slot >> 2;                     // 0..15
    const int b = bh >> 4, nh = bh & 15;
    const int q0 = qb * 128;
    const int wq = qg * 32;
    const int koff = kh * KHALF;                  // 0 or 1024

    const unsigned short* Qp = Qr + (size_t)bh * L_SEQ * HDIM;
    const unsigned short* Kp = Kr + (size_t)bh * L_SEQ * HDIM;
    const unsigned short* Vp = Vt + (size_t)bh * HDIM * L_SEQ;

    // Q fragments: 32 q rows per wave (q = q0 + wq + qt*16 + ml).
    bf16x8 qf[2][2];
#pragma unroll
    for (int qt = 0; qt < 2; ++qt)
#pragma unroll
        for (int c = 0; c < 2; ++c)
            qf[qt][c] = *(const bf16x8*)(Qp + (size_t)(q0 + wq + qt * 16 + ml) * HDIM + c * 32 + kq * 8);

    float li[2] = {0.f, 0.f};
    f32x4 o[2][4];
#pragma unroll
    for (int qt = 0; qt < 2; ++qt)
#pragma unroll
        for (int ht = 0; ht < 4; ++ht) o[qt][ht] = (f32x4){0.f, 0.f, 0.f, 0.f};

    unsigned short* Pw = lds + 16384 + w * 1024;

    // Staging (per kh-half tile of 32 keys):
    //  K: wave stages rows [qg*8, +8) of the 32x64 tile   (1 issue, 1 KB)
    //  V: wave stages h-rows [qg*16, +16) of the 64x32 tile (1 issue, 1 KB)
    const int srow8 = lane >> 3;
    const int sch   = (lane & 7) ^ srow8;                 // K read-swz inverse
    const unsigned short* gK = Kp + (size_t)(koff + qg * 8 + srow8) * HDIM + sch * 8;
    const int vrow = lane >> 2;
    const int vch  = (lane & 3) ^ (vrow & 3);             // V read-swz inverse
    const unsigned short* gV = Vp + (size_t)(qg * 16 + vrow) * L_SEQ + koff + vch * 8;

#define STAGE(kt, bf)                                                           \
    do {                                                                        \
        gl2lds16(gK + (size_t)(kt) * KVBLK * HDIM,                              \
                 lds + ((bf) * 2 + kh) * 2048 + qg * 512);                      \
        gl2lds16(gV + (kt) * KVBLK,                                             \
                 lds + 8192 + ((bf) * 2 + kh) * 2048 + qg * 512);               \
    } while (0)

    // Mask-bias quads: key = koff + kt*32 + nt*16 + kq*4 + r (C/D row layout).
    const float* fbp = fbias + (size_t)b * L_SEQ + koff + kq * 4;
    f32x4 bcur[2], bnext[2];
#pragma unroll
    for (int nt = 0; nt < 2; ++nt) bcur[nt] = *(const f32x4*)(fbp + nt * 16);

    STAGE(0, 0);

    for (int kt = 0; kt < NKT; ++kt) {
        const int buf = kt & 1;
        __syncthreads();                       // tile kt staged (all 8 waves)
        if (kt + 1 < NKT) {
            STAGE(kt + 1, buf ^ 1);
#pragma unroll
            for (int nt = 0; nt < 2; ++nt)
                bnext[nt] = *(const f32x4*)(fbp + (kt + 1) * KVBLK + nt * 16);
        }

        const unsigned short* Kb = lds + (buf * 2 + kh) * 2048;
        const unsigned short* Vb = lds + 8192 + (buf * 2 + kh) * 2048;

        // S^T = K·Q^T + maskbias : 32 keys x 32 q per wave.
        f32x4 st[2][2];
#pragma unroll
        for (int nt = 0; nt < 2; ++nt) {
            const int R = nt * 16 + ml;
            const bf16x8 kf0 = *(const bf16x8*)&Kb[R * 64 + ((kq ^ (R & 7)) << 3)];
            const bf16x8 kf1 = *(const bf16x8*)&Kb[R * 64 + (((4 + kq) ^ (R & 7)) << 3)];
#pragma unroll
            for (int qt = 0; qt < 2; ++qt) {
                f32x4 c = MFMA(kf0, qf[qt][0], bcur[nt]);
                c = MFMA(kf1, qf[qt][1], c);
                st[qt][nt] = c;
            }
        }

        // Fixed-max softmax; P -> per-wave LDS (rows 32 q x 32 k, swizzled).
#pragma unroll
        for (int qt = 0; qt < 2; ++qt) {
#pragma unroll
            for (int nt = 0; nt < 2; ++nt) {
                float p[4];
#pragma unroll
                for (int r = 0; r < 4; ++r) {
                    p[r] = EXP2(st[qt][nt][r]);
                    li[qt] += p[r];
                }
                uint2 pk;
                pk.x = pkbf(p[0], p[1]);
                pk.y = pkbf(p[2], p[3]);
                const int row = qt * 16 + ml;
                const int cg = (nt * 2 + (kq >> 1)) ^ (row & 3);
                *(uint2*)&Pw[row * 32 + (cg << 3) + (kq & 1) * 4] = pk;
            }
        }
        WAVE_FENCE();

        // O^T += V^T·P (32-key slab: one MFMA per (qt,ht)).
        bf16x8 pf[2];
#pragma unroll
        for (int qt = 0; qt < 2; ++qt) {
            const int row = qt * 16 + ml;
            pf[qt] = *(const bf16x8*)&Pw[row * 32 + ((kq ^ (row & 3)) << 3)];
        }
#pragma unroll
        for (int ht = 0; ht < 4; ++ht) {
            const int R = ht * 16 + ml;
            const bf16x8 vf = *(const bf16x8*)&Vb[R * 32 + ((kq ^ (R & 3)) << 3)];
#pragma unroll
            for (int qt = 0; qt < 2; ++qt)
                o[qt][ht] = MFMA(vf, pf[qt], o[qt][ht]);
        }
        WAVE_FENCE();  // Pw reads done before next tile overwrites

#pragma unroll
        for (int nt = 0; nt < 2; ++nt) bcur[nt] = bnext[nt];
    }
#undef STAGE

    // li spans lanes ml, ml+16, ml+32, ml+48 -> per-kh partial.
#pragma unroll
    for (int qt = 0; qt < 2; ++qt) {
        li[qt] += __shfl_xor(li[qt], 16);
        li[qt] += __shfl_xor(li[qt], 32);
    }

    // --- kh combine: kh=1 dumps o (f32 -> dead K/V region, 32 KB) + li; ---
    // --- kh=0 adds and owns the epilogue.                                ---
    float* osc = (float*)lds;                      // [qg][idx 0..7][lane] f32x4
    float* lis = (float*)(lds + 24576);            // [qg*32 + qt*16 + ml]
    __syncthreads();                               // all K/V reads done
    if (kh == 1) {
#pragma unroll
        for (int qt = 0; qt < 2; ++qt)
#pragma unroll
            for (int ht = 0; ht < 4; ++ht)
                *(f32x4*)(osc + qg * 2048 + (qt * 4 + ht) * 256 + lane * 4) = o[qt][ht];
        if (kq == 0) {
            lis[qg * 32 + ml]      = li[0];
            lis[qg * 32 + 16 + ml] = li[1];
        }
    }
    __syncthreads();                               // publish partials
    if (kh == 1) return;

#pragma unroll
    for (int qt = 0; qt < 2; ++qt) {
#pragma unroll
        for (int ht = 0; ht < 4; ++ht)
            o[qt][ht] += *(const f32x4*)(osc + qg * 2048 + (qt * 4 + ht) * 256 + lane * 4);
        li[qt] += lis[qg * 32 + qt * 16 + ml];
    }
    const float inv[2] = {1.f / li[0], 1.f / li[1]};

    // Epilogue (R3-identical): transpose 32q x 64h via 32x64-short Pe region.
    unsigned short* Pe = lds + 16384 + qg * 2048;
    const int qr = lane >> 2, quarter = lane & 3;
    const int rc0 = (quarter * 2) ^ (qr & 7), rc1 = (quarter * 2 + 1) ^ (qr & 7);

#pragma unroll
    for (int qt = 0; qt < 2; ++qt)
#pragma unroll
        for (int ht = 0; ht < 4; ++ht) {
            uint2 pk;
            pk.x = pkbf(o[qt][ht][0] * inv[qt], o[qt][ht][1] * inv[qt]);
            pk.y = pkbf(o[qt][ht][2] * inv[qt], o[qt][ht][3] * inv[qt]);
            const int row = qt * 16 + ml;
            const int ck = ht * 2 + (kq >> 1);
            *(uint2*)&Pe[row * 64 + ((ck ^ (ml & 7)) << 3) + (kq & 1) * 4] = pk;
        }
    WAVE_FENCE();
#pragma unroll
    for (int qt = 0; qt < 2; ++qt) {
        const size_t gbase = ((size_t)b * L_SEQ + q0 + wq + qt * 16 + qr) * DMODEL
                             + nh * 64 + quarter * 16;
        const uint4 d0 = *(const uint4*)&Pe[(qt * 16 + qr) * 64 + (rc0 << 3)];
        const uint4 d1 = *(const uint4*)&Pe[(qt * 16 + qr) * 64 + (rc1 << 3)];
        *(uint4*)&AOhi[gbase]     = d0;
        *(uint4*)&AOhi[gbase + 8] = d1;
    }
    WAVE_FENCE();
#pragma unroll
    for (int qt = 0; qt < 2; ++qt)
#pragma unroll
        for (int ht = 0; ht < 4; ++ht) {
            float lo[4];
#pragma unroll
            for (int r = 0; r < 4; ++r) {
                const float v = o[qt][ht][r] * inv[qt];
                const float hf = __uint_as_float((__float_as_uint(v) + 0x8000u) & 0xffff0000u);
                lo[r] = v - hf;
            }
            uint2 pk;
            pk.x = pkbf(lo[0], lo[1]);
            pk.y = pkbf(lo[2], lo[3]);
            const int row = qt * 16 + ml;
            const int ck = ht * 2 + (kq >> 1);
            *(uint2*)&Pe[row * 64 + ((ck ^ (ml & 7)) << 3) + (kq & 1) * 4] = pk;
        }
    WAVE_FENCE();
#pragma unroll
    for (int qt = 0; qt < 2; ++qt) {
        const size_t gbase = ((size_t)b * L_SEQ + q0 + wq + qt * 16 + qr) * DMODEL
                             + nh * 64 + quarter * 16;
        const uint4 d0 = *(const uint4*)&Pe[(qt * 16 + qr) * 64 + (rc0 << 3)];
        const uint4 d1 = *(const uint4*)&Pe[(qt * 16 + qr) * 64 + (rc1 << 3)];
        *(uint4*)&AOlo[gbase]     = d0;
        *(uint4*)&AOlo[gbase + 8] = d1;
    }
}

// ---------------------------------------------------------------------------
// Kernel C: out = AO @ Wo^T + bo, 3-term bf16-split. 128x64 tiles, 512
// blocks = 2 blocks/CU. id%8 == by%8 -> A-panel XCD colocation.
// ---------------------------------------------------------------------------
__global__ __launch_bounds__(256) void oproj_kernel(
    const unsigned short* __restrict__ Ahi_g, const unsigned short* __restrict__ Alo_g,
    const unsigned short* __restrict__ Whi_g, const unsigned short* __restrict__ Wlo_g,
    const float* __restrict__ bias, float* __restrict__ out)
{
    const int id = blockIdx.x;
    const int bxn = id >> 5, by = id & 31;

    __shared__ __align__(16) unsigned short Ah[128 * 32], Al[128 * 32];  // 8 KB ea
    __shared__ __align__(16) unsigned short Bh[64 * 32],  Bl[64 * 32];   // 4 KB ea

    const int tid  = threadIdx.x;
    const int wave = tid >> 6, lane = tid & 63;
    const int ml = lane & 15, kq = lane >> 4;
    const int m0 = by * 128, n0 = bxn * 64;
    const int wm = (wave & 1) * 64, wn = (wave >> 1) * 32;

    f32x4 acc[4][2];
#pragma unroll
    for (int i = 0; i < 4; ++i)
#pragma unroll
        for (int j = 0; j < 2; ++j) acc[i][j] = (f32x4){0.f, 0.f, 0.f, 0.f};

    const int rl  = lane >> 2;                       // 0..15 rows per issue
    const int pch = (lane & 3) ^ ((lane >> 3) & 3);
    const int prowA = wave * 32 + rl;
    const int prowB = wave * 16 + rl;
    const unsigned short* gAh = Ahi_g + (size_t)(m0 + prowA) * DMODEL + pch * 8;
    const unsigned short* gAl = Alo_g + (size_t)(m0 + prowA) * DMODEL + pch * 8;
    const unsigned short* gBh = Whi_g + (size_t)(n0 + prowB) * DMODEL + pch * 8;
    const unsigned short* gBl = Wlo_g + (size_t)(n0 + prowB) * DMODEL + pch * 8;
    unsigned short* lAh = Ah + wave * 1024;
    unsigned short* lAl = Al + wave * 1024;
    unsigned short* lBh = Bh + wave * 512;
    unsigned short* lBl = Bl + wave * 512;

    for (int kc = 0; kc < DMODEL; kc += 32) {
#pragma unroll
        for (int qq = 0; qq < 2; ++qq) {
            const size_t go = kc + (size_t)qq * 16 * DMODEL;
            gl2lds16(gAh + go, lAh + qq * 512);
            gl2lds16(gAl + go, lAl + qq * 512);
        }
        gl2lds16(gBh + kc, lBh);
        gl2lds16(gBl + kc, lBl);
        __syncthreads();

        bf16x8 ah[4], al[4], bh_[2], bl_[2];
#pragma unroll
        for (int i = 0; i < 4; ++i) {
            const int Ra = wm + i * 16 + ml;
            const int sa = Ra * 32 + ((kq ^ ((Ra >> 1) & 3)) << 3);
            ah[i] = *(const bf16x8*)&Ah[sa];
            al[i] = *(const bf16x8*)&Al[sa];
        }
#pragma unroll
        for (int j = 0; j < 2; ++j) {
            const int Rb = wn + j * 16 + ml;
            const int sb = Rb * 32 + ((kq ^ ((Rb >> 1) & 3)) << 3);
            bh_[j] = *(const bf16x8*)&Bh[sb];
            bl_[j] = *(const bf16x8*)&Bl[sb];
        }
#pragma unroll
        for (int i = 0; i < 4; ++i)
#pragma unroll
            for (int j = 0; j < 2; ++j) {
                acc[i][j] = MFMA(ah[i], bh_[j], acc[i][j]);
                acc[i][j] = MFMA(al[i], bh_[j], acc[i][j]);
                acc[i][j] = MFMA(ah[i], bl_[j], acc[i][j]);
            }
        __syncthreads();
    }

#pragma unroll
    for (int jt = 0; jt < 2; ++jt) {
        const int col = n0 + wn + jt * 16 + ml;
        const float bv = bias[col];
#pragma unroll
        for (int it = 0; it < 4; ++it)
#pragma unroll
            for (int r = 0; r < 4; ++r) {
                const int row = m0 + wm + it * 16 + kq * 4 + r;
                out[(size_t)row * DMODEL + col] = acc[it][jt][r] + bv;
            }
    }
}

extern "C" void kernel_launch(void* const* d_in, const int* in_sizes, int n_in,
                              void* d_out, int out_size, void* d_ws, size_t ws_size,
                              hipStream_t stream)
{
    (void)in_sizes; (void)n_in; (void)out_size; (void)ws_size;
    const float* q    = (const float*)d_in[0];
    const float* k    = (const float*)d_in[1];
    const float* v    = (const float*)d_in[2];
    const int*   mask = (const int*)d_in[3];
    const float* Wq   = (const float*)d_in[4];
    const float* bq   = (const float*)d_in[5];
    const float* Wk   = (const float*)d_in[6];
    const float* bk   = (const float*)d_in[7];
    const float* Wv   = (const float*)d_in[8];
    const float* bv   = (const float*)d_in[9];
    const float* Wo   = (const float*)d_in[10];
    const float* bo   = (const float*)d_in[11];
    float* out = (float*)d_out;

    const size_t HE = (size_t)BATCH * NHEAD * L_SEQ * HDIM;   // 4,194,304
    const size_t DD = (size_t)DMODEL * DMODEL;                // 1,048,576
    unsigned short* Xb   = (unsigned short*)d_ws;             // 24 MB
    unsigned short* Wb   = Xb + 3 * HE;                       // 6 MB
    unsigned short* Qr   = Wb + 3 * DD;
    unsigned short* Kr   = Qr + HE;
    unsigned short* Vt   = Kr + HE;
    unsigned short* Whi  = Vt + HE;
    unsigned short* Wlo  = Whi + DD;
    float* fbias = (float*)(Wlo + DD);                        // 16 KB
    float2* ropetab = (float2*)(fbias + (size_t)BATCH * L_SEQ);
    unsigned short* AOhi = Xb;          // alias Xb (qkv done reading)
    unsigned short* AOlo = Xb + HE;

    prep_kernel<<<dim3(2048, 8), dim3(256), 0, stream>>>(
        q, k, v, Wq, Wk, Wv, Wo, mask, Xb, Wb, Whi, Wlo, ropetab, fbias);

    qkv_kernel<<<dim3(768), dim3(256), 0, stream>>>(Xb, Wb, bq, bk, bv, ropetab, Qr, Kr, Vt);

    attn_kernel<<<dim3(512), dim3(512), 0, stream>>>(Qr, Kr, Vt, fbias, AOhi, AOlo);

    oproj_kernel<<<dim3(512), dim3(256), 0, stream>>>(AOhi, AOlo, Whi, Wlo, bo, out);
}